// Round 16
// baseline (308.922 us; speedup 1.0000x reference)
//
#include <hip/hip_runtime.h>
#include <hip/hip_cooperative_groups.h>

namespace cg = cooperative_groups;

#define NPX (2160*3840)
#define EPS 1e-5f

typedef float __attribute__((ext_vector_type(4))) fx4;

// ---------------- resize along W: (3,2160,3840) -> (3,2160,256) ----------------
__global__ __launch_bounds__(256) void resize_w_kernel(const float* __restrict__ img,
                                                       float* __restrict__ tmp) {
  __shared__ __align__(16) float row[3872];   // 16 zero | 3840 | 16 zero
  const int bh = blockIdx.x;            // c*2160 + h
  const float* src = img + (size_t)bh * 3840;
  const int tid = threadIdx.x;          // 256
  if (tid < 16) { row[tid] = 0.f; row[3856 + tid] = 0.f; }
  const float4* s4 = (const float4*)src;
  float4* r4 = (float4*)(row + 16);
  for (int i = tid; i < 960; i += 256) r4[i] = s4[i];
  __syncthreads();
  const int i = tid;
  const float* rp = row + 15*i + 9;     // = 16 + center-14
  float acc = 0.f;
  #pragma unroll
  for (int k = 0; k < 29; ++k) {
    const float w = (float)(15 - (k < 14 ? 14 - k : k - 14));
    acc = fmaf(w, rp[k], acc);
  }
  const float rcpw = (i == 0 || i == 255) ? (1.f/197.f) : (1.f/225.f);
  tmp[bh*256 + i] = acc * rcpw;
}

// ---------------- resize along H: (3,2160,256) -> (3,256,256) ----------------
__global__ __launch_bounds__(256) void resize_h_kernel(const float* __restrict__ tmp,
                                                       float* __restrict__ dst) {
  const int c = blockIdx.x >> 8;
  const int oh = blockIdx.x & 255;
  const int ow = threadIdx.x;           // 256
  const float sf = ((float)oh + 0.5f) * 8.4375f - 0.5f;
  int lo = (int)ceilf(sf - 8.4375f); if (lo < 0) lo = 0;
  int hi = (int)floorf(sf + 8.4375f); if (hi > 2159) hi = 2159;
  float acc = 0.f, wsum = 0.f;
  for (int j = lo; j <= hi; ++j) {
    const float w = 1.f - fabsf(sf - (float)j) * (16.f/135.f);
    acc = fmaf(w, tmp[(c*2160 + j)*256 + ow], acc);
    wsum += w;
  }
  dst[blockIdx.x*256 + ow] = acc / wsum;
}

// ---------------- conv stage (device fn): conv3x3(s2,p1)+norm-on-stage+lrelu+stats ----------------
template<int CIN,int CICHUNK,int HIN,int WIN,int HOUT,int WOUT,int TH,int NPIN>
__device__ __forceinline__ void conv_stage(int unit, int tid, float* smem,
    const float* __restrict__ in, const float* __restrict__ wt, const float* __restrict__ bias,
    const float* __restrict__ pin, const float* __restrict__ gin, const float* __restrict__ bin,
    float* __restrict__ out, float2* __restrict__ pout) {
  constexpr int NTW = WOUT/16;
  constexpr int NT  = (HOUT/TH)*NTW;
  constexpr int NCHUNK = CIN/CICHUNK;
  constexpr int HROWS = 2*TH + 1;
  constexpr int SLOTS = CICHUNK*HROWS*9;       // float4 slots per chunk
  constexpr float PHW_INV = 1.f/(float)(HIN*WIN);
  constexpr int WOFF = (CICHUNK*HROWS*36 + CIN*9 + 2*CIN + 1) & ~1;

  float* sx = smem;
  float* wl = smem + CICHUNK*HROWS*36;
  float* sA = wl + CIN*9;
  float* sB = sA + CIN;
  float2* wred = (float2*)(smem + WOFF);

  const int co = unit / NT;
  const int t  = unit % NT;
  const int oh0 = (t / NTW)*TH, ow0 = (t % NTW)*16;

  for (int i = tid; i < CIN*9; i += 256) wl[i] = wt[co*CIN*9 + i];
  if (NPIN > 0) {
    if (tid < CIN) {
      const float2* p2 = (const float2*)pin;
      float s = 0.f, q = 0.f;
      #pragma unroll 4
      for (int k = 0; k < NPIN; ++k) { float2 p = p2[tid*NPIN + k]; s += p.x; q += p.y; }
      const float m = s * PHW_INV;
      float var = q * PHW_INV - m*m; var = fmaxf(var, 0.f);
      const float A = gin[tid] * rsqrtf(var + EPS);
      sA[tid] = A; sB[tid] = bin[tid] - m*A;
    }
  }
  __syncthreads();

  const int ohl = tid >> 4, owl = tid & 15;
  const bool active = (ohl < TH);
  float acc = bias[co];

  for (int cc = 0; cc < NCHUNK; ++cc) {
    if (cc) __syncthreads();
    const int cb = cc*CICHUNK;
    for (int i = tid; i < SLOTS; i += 256) {
      const int ci_l = i / (HROWS*9);
      const int rem  = i - ci_l*(HROWS*9);
      const int r = rem / 9, q = rem - r*9;
      const int grow = 2*oh0 - 1 + r;
      const int ga   = 2*ow0 - 4 + 4*q;
      float4 v = make_float4(0.f,0.f,0.f,0.f);
      if (grow >= 0 && grow < HIN && ga >= 0) {
        v = *(const float4*)(in + ((size_t)(cb+ci_l)*HIN + grow)*WIN + ga);
        if (NPIN > 0) {
          const float A = sA[cb+ci_l], B = sB[cb+ci_l];
          v.x = fmaf(A, v.x, B); v.y = fmaf(A, v.y, B);
          v.z = fmaf(A, v.z, B); v.w = fmaf(A, v.w, B);
        }
      }
      *(float4*)&sx[(ci_l*HROWS + r)*36 + q*4] = v;
    }
    __syncthreads();
    if (active) {
      #pragma unroll 4
      for (int ci_l = 0; ci_l < CICHUNK; ++ci_l) {
        const float* sp = sx + ci_l*(HROWS*36);
        const float* wp = wl + (cb+ci_l)*9;
        #pragma unroll
        for (int kh = 0; kh < 3; ++kh) {
          const float* rp = sp + (2*ohl + kh)*36 + 3 + 2*owl;
          acc = fmaf(rp[0], wp[kh*3+0], acc);
          acc = fmaf(rp[1], wp[kh*3+1], acc);
          acc = fmaf(rp[2], wp[kh*3+2], acc);
        }
      }
    }
  }

  acc = acc >= 0.f ? acc : 0.2f*acc;
  if (active) out[(size_t)co*HOUT*WOUT + (oh0+ohl)*WOUT + ow0 + owl] = acc;

  float s = active ? acc : 0.f;
  float q = active ? acc*acc : 0.f;
  #pragma unroll
  for (int off = 32; off > 0; off >>= 1) {
    s += __shfl_down(s, off);
    q += __shfl_down(q, off);
  }
  if ((tid & 63) == 0) wred[tid >> 6] = make_float2(s, q);
  __syncthreads();
  if (tid == 0) {
    const float S = wred[0].x + wred[1].x + wred[2].x + wred[3].x;
    const float Q = wred[0].y + wred[1].y + wred[2].y + wred[3].y;
    pout[co*NT + t] = make_float2(S, Q);
  }
}

// ---------------- conv5 stage: (128ci,16x16 -> 1co,8x8) + lrelu + w6 dot partials ----------------
__device__ __forceinline__ void conv5_stage(int co, int tid, float* smem,
    const float* __restrict__ in, const float* __restrict__ wt, const float* __restrict__ bias,
    const float* __restrict__ pin, const float* __restrict__ gin, const float* __restrict__ bin,
    const float* __restrict__ w6, float* __restrict__ part) {
  float* sx  = smem;            // 32*17*20 = 10880
  float* wl  = smem + 10880;    // 1152
  float* sA  = smem + 12032;    // 128
  float* sB  = smem + 12160;    // 128
  float* red = smem + 12288;    // 256
  for (int i = tid; i < 1152; i += 256) wl[i] = wt[co*1152 + i];
  if (tid < 128) {
    const float2* p2 = (const float2*)pin;
    const float2 pa = p2[tid*2], pb = p2[tid*2+1];
    const float m = (pa.x + pb.x) * (1.f/256.f);
    float var = (pa.y + pb.y) * (1.f/256.f) - m*m; var = fmaxf(var, 0.f);
    const float A = gin[tid] * rsqrtf(var + EPS);
    sA[tid] = A; sB[tid] = bin[tid] - m*A;
  }
  __syncthreads();

  const int px = tid & 63, q = tid >> 6;
  const int ohl = px >> 3, owl = px & 7;
  float acc = 0.f;
  for (int cc = 0; cc < 4; ++cc) {
    if (cc) __syncthreads();
    const int cb = cc*32;
    for (int i = tid; i < 32*17*5; i += 256) {
      const int ci_l = i / 85;
      const int rem  = i - ci_l*85;
      const int r = rem / 5, qq = rem - r*5;
      const int grow = r - 1;
      const int ga   = 4*qq - 4;
      float4 v = make_float4(0.f,0.f,0.f,0.f);
      if (grow >= 0 && grow < 16 && ga >= 0) {
        v = *(const float4*)(in + ((size_t)(cb+ci_l)*16 + grow)*16 + ga);
        const float A = sA[cb+ci_l], B = sB[cb+ci_l];
        v.x = fmaf(A, v.x, B); v.y = fmaf(A, v.y, B);
        v.z = fmaf(A, v.z, B); v.w = fmaf(A, v.w, B);
      }
      *(float4*)&sx[(ci_l*17 + r)*20 + qq*4] = v;
    }
    __syncthreads();
    #pragma unroll 2
    for (int k = 0; k < 8; ++k) {
      const int ci_l = q*8 + k;
      const float* sp = sx + ci_l*340;
      const float* wp = wl + (cb+ci_l)*9;
      #pragma unroll
      for (int kh = 0; kh < 3; ++kh) {
        const float* rp = sp + (2*ohl + kh)*20 + 3 + 2*owl;
        acc = fmaf(rp[0], wp[kh*3+0], acc);
        acc = fmaf(rp[1], wp[kh*3+1], acc);
        acc = fmaf(rp[2], wp[kh*3+2], acc);
      }
    }
  }
  red[tid] = acc;
  __syncthreads();
  if (tid < 64) {
    float a = red[tid] + red[tid+64] + red[tid+128] + red[tid+192] + bias[co];
    a = a >= 0.f ? a : 0.2f*a;
    #pragma unroll
    for (int j = 0; j < 3; ++j) {
      float v = a * w6[(j*128 + co)*64 + tid];
      #pragma unroll
      for (int off = 32; off > 0; off >>= 1) v += __shfl_down(v, off);
      if (tid == 0) part[co*3 + j] = v;
    }
  }
}

// ---------------- blend_pack stage (even-pair layout) ----------------
__device__ __forceinline__ void bp_stage(int b, int tid, float* smem,
    const float* __restrict__ l0, const float* __restrict__ l1, const float* __restrict__ l2,
    const float* __restrict__ part, const float* __restrict__ b6,
    unsigned* __restrict__ flp) {
  float* sp   = smem;       // 3
  float* sred = smem + 4;   // 2*3
  float a0 = 0.f, a1 = 0.f, a2 = 0.f;
  if (tid < 128) { a0 = part[tid*3]; a1 = part[tid*3+1]; a2 = part[tid*3+2]; }
  #pragma unroll
  for (int off = 32; off > 0; off >>= 1) {
    a0 += __shfl_down(a0, off);
    a1 += __shfl_down(a1, off);
    a2 += __shfl_down(a2, off);
  }
  if (tid < 128 && (tid & 63) == 0) {
    sred[(tid >> 6)*3 + 0] = a0; sred[(tid >> 6)*3 + 1] = a1; sred[(tid >> 6)*3 + 2] = a2;
  }
  __syncthreads();
  if (tid < 3) sp[tid] = sred[tid] + sred[3 + tid] + b6[tid];
  __syncthreads();
  const int i = b*256 + tid;
  if (i >= 3*18513) return;
  const int c = i / 18513, rem = i - c*18513;
  const int row = rem / 17, j = rem - row*17;
  const int src = c*35937 + row*33 + 2*j;
  const float v0 = sp[0]*l0[src] + sp[1]*l1[src] + sp[2]*l2[src];
  float v1 = 0.f;
  if (2*j + 1 <= 32) v1 = sp[0]*l0[src+1] + sp[1]*l1[src+1] + sp[2]*l2[src+1];
  unsigned u0 = __float_as_uint(v0); u0 = (u0 + 0x7fffu + ((u0>>16)&1u)) >> 16;
  unsigned u1 = __float_as_uint(v1); u1 = (u1 + 0x7fffu + ((u1>>16)&1u)) >> 16;
  flp[c*18516 + rem] = u0 | (u1 << 16);
}

// ---------------- cooperative fused classifier tail: conv1..conv5 + blend_pack ----------------
struct TailArgs {
  const float *r256, *w1, *b1;
  const float *w2, *b2, *g1, *be1;
  const float *w3, *b3, *g2, *be2;
  const float *w4, *b4, *g3, *be3;
  const float *w5, *b5, *g4, *be4;
  const float *w6, *b6;
  const float *l0, *l1, *l2;
  float *c1, *c2, *c3, *c4;
  float *part1, *part2, *part3, *part4, *part6;
  unsigned *flp;
};

__global__ __launch_bounds__(256) void tail_fused(TailArgs a) {
  __shared__ __align__(16) float smem[19376];   // 77.5 KB arena, 2 blocks/CU
  cg::grid_group grid = cg::this_grid();
  const int b = blockIdx.x;        // 256 blocks
  const int tid = threadIdx.x;     // 256 threads

  // conv1: 16co x 64 tiles = 1024 units, 4 per block
  for (int u = b; u < 1024; u += 256) {
    conv_stage<3,3,256,256,128,128,16,0>(u, tid, smem, a.r256, a.w1, a.b1,
        nullptr, nullptr, nullptr, a.c1, (float2*)a.part1);
    __syncthreads();
  }
  grid.sync();
  // conv2: 32co x 16 tiles = 512 units, 2 per block
  for (int u = b; u < 512; u += 256) {
    conv_stage<16,16,128,128,64,64,16,64>(u, tid, smem, a.c1, a.w2, a.b2,
        a.part1, a.g1, a.be1, a.c2, (float2*)a.part2);
    __syncthreads();
  }
  grid.sync();
  // conv3: 64co x 4 tiles = 256 units
  conv_stage<32,16,64,64,32,32,16,16>(b, tid, smem, a.c2, a.w3, a.b3,
      a.part2, a.g2, a.be2, a.c3, (float2*)a.part3);
  grid.sync();
  // conv4: 128co x 2 tiles (TH=8) = 256 units
  conv_stage<64,16,32,32,16,16,8,4>(b, tid, smem, a.c3, a.w4, a.b4,
      a.part3, a.g3, a.be3, a.c4, (float2*)a.part4);
  grid.sync();
  // conv5 + w6 dot: 128 units
  if (b < 128)
    conv5_stage(b, tid, smem, a.c4, a.w5, a.b5, a.part4, a.g4, a.be4, a.w6, a.part6);
  grid.sync();
  // blend + pack: 3*18513 = 55539 elems over 65536 threads
  bp_stage(b, tid, smem, a.l0, a.l1, a.l2, a.part6, a.b6, a.flp);
}

// ---------------- trilinear: XCD-swizzled (3 channels of a chunk share an XCD's L2) ----------------
__global__ __launch_bounds__(1024, 8) void trilinear_kernel(const float* __restrict__ img,
    const unsigned* __restrict__ flp, float* __restrict__ out) {
  __shared__ unsigned slut[18516];     // 74.1 KB -> 2 blocks/CU, 32 waves
  const int tid = threadIdx.x;
  const int b = blockIdx.x;            // 768 = 8 XCD * 32 chunks * 3 ch
  const int x = b & 7;
  const int j = b >> 3;                // 0..95
  const int chunk = x*32 + j/3;
  const int c     = j % 3;
  {
    uint4* d4 = (uint4*)slut;
    const uint4* s4 = (const uint4*)(flp + c*18516);
    for (int i = tid; i < 4629; i += 1024) d4[i] = s4[i];
  }
  __syncthreads();
  const int p0 = chunk * 32400;        // 256 chunks * 32400 = 8,294,400
  const float* imR = img + p0;
  const float* imG = img + NPX + p0;
  const float* imB = img + 2*NPX + p0;
  float* op = out + (size_t)c*NPX + p0;
  for (int g = tid; g < 4050; g += 1024) {
    const int pA = 4*g;
    const int pB = pA + 16200;
    float rv[8], gv[8], bv[8], ov[8];
    {
      const float4 A = *(const float4*)(imR + pA);
      const float4 B = *(const float4*)(imR + pB);
      rv[0]=A.x; rv[1]=A.y; rv[2]=A.z; rv[3]=A.w;
      rv[4]=B.x; rv[5]=B.y; rv[6]=B.z; rv[7]=B.w;
    }
    {
      const float4 A = *(const float4*)(imG + pA);
      const float4 B = *(const float4*)(imG + pB);
      gv[0]=A.x; gv[1]=A.y; gv[2]=A.z; gv[3]=A.w;
      gv[4]=B.x; gv[5]=B.y; gv[6]=B.z; gv[7]=B.w;
    }
    {
      const float4 A = *(const float4*)(imB + pA);
      const float4 B = *(const float4*)(imB + pB);
      bv[0]=A.x; bv[1]=A.y; bv[2]=A.z; bv[3]=A.w;
      bv[4]=B.x; bv[5]=B.y; bv[6]=B.z; bv[7]=B.w;
    }
    #pragma unroll
    for (int k = 0; k < 8; ++k) {
      const float xr = rv[k]*32.f, xg = gv[k]*32.f, xb = bv[k]*32.f;
      // img is uniform [0,1): (int)x <= 31 guaranteed
      const int ir = (int)xr, ig = (int)xg, ib = (int)xb;
      const float fr = xr - (float)ir;
      const float fg = xg - (float)ig;
      const float fb = xb - (float)ib;
      const int rb = (ib*33 + ig)*17;
      const int jA = rb + (ir >> 1);
      const int jB = rb + ((ir + 1) >> 1);
      const unsigned sh = (ir & 1) * 16;
      const unsigned w0a = slut[jA],       w0b = slut[jB];
      const unsigned w1a = slut[jA + 17],  w1b = slut[jB + 17];
      const unsigned w2a = slut[jA + 561], w2b = slut[jB + 561];
      const unsigned w3a = slut[jA + 578], w3b = slut[jB + 578];
      // alignbit(hi=wb, lo=wa, sh): lo16 = v[ir], hi16 = v[ir+1]
      const unsigned r0 = __builtin_amdgcn_alignbit(w0b, w0a, sh);
      const unsigned r1 = __builtin_amdgcn_alignbit(w1b, w1a, sh);
      const unsigned r2 = __builtin_amdgcn_alignbit(w2b, w2a, sh);
      const unsigned r3 = __builtin_amdgcn_alignbit(w3b, w3a, sh);
      const float v000 = __uint_as_float(r0 << 16), v001 = __uint_as_float(r0 & 0xffff0000u);
      const float v010 = __uint_as_float(r1 << 16), v011 = __uint_as_float(r1 & 0xffff0000u);
      const float v100 = __uint_as_float(r2 << 16), v101 = __uint_as_float(r2 & 0xffff0000u);
      const float v110 = __uint_as_float(r3 << 16), v111 = __uint_as_float(r3 & 0xffff0000u);
      const float a0 = fmaf(fr, v001 - v000, v000);
      const float a1 = fmaf(fr, v011 - v010, v010);
      const float a2 = fmaf(fr, v101 - v100, v100);
      const float a3 = fmaf(fr, v111 - v110, v110);
      const float lo = fmaf(fg, a1 - a0, a0);
      const float hi = fmaf(fg, a3 - a2, a2);
      ov[k] = fmaf(fb, hi - lo, lo);
    }
    fx4 r0 = {ov[0], ov[1], ov[2], ov[3]};
    fx4 r1 = {ov[4], ov[5], ov[6], ov[7]};
    __builtin_nontemporal_store(r0, (fx4*)(op + pA));
    __builtin_nontemporal_store(r1, (fx4*)(op + pB));
  }
}

extern "C" void kernel_launch(void* const* d_in, const int* in_sizes, int n_in,
                              void* d_out, int out_size, void* d_ws, size_t ws_size,
                              hipStream_t stream) {
  const float* img  = (const float*)d_in[0];
  const float* lut0 = (const float*)d_in[1];
  const float* lut1 = (const float*)d_in[2];
  const float* lut2 = (const float*)d_in[3];
  const float* w1 = (const float*)d_in[4];  const float* b1  = (const float*)d_in[5];
  const float* g1 = (const float*)d_in[6];  const float* be1 = (const float*)d_in[7];
  const float* w2 = (const float*)d_in[8];  const float* b2  = (const float*)d_in[9];
  const float* g2 = (const float*)d_in[10]; const float* be2 = (const float*)d_in[11];
  const float* w3 = (const float*)d_in[12]; const float* b3  = (const float*)d_in[13];
  const float* g3 = (const float*)d_in[14]; const float* be3 = (const float*)d_in[15];
  const float* w4 = (const float*)d_in[16]; const float* b4  = (const float*)d_in[17];
  const float* g4 = (const float*)d_in[18]; const float* be4 = (const float*)d_in[19];
  const float* w5 = (const float*)d_in[20]; const float* b5  = (const float*)d_in[21];
  const float* w6 = (const float*)d_in[22]; const float* b6  = (const float*)d_in[23];

  float* ws = (float*)d_ws;
  float* tmp   = ws;                 // 3*2160*256 = 1,658,880 (dead after resize_h)
  float* r256  = ws + 1658880;       // 3*256*256 = 196,608
  float* c1    = ws;                 // 16*128*128 = 262,144 (tmp dead)
  float* c2    = ws + 262144;        // 32*64*64  = 131,072
  float* c3    = ws + 393216;        // 64*32*32  =  65,536
  float* c4    = ws + 458752;        // 128*16*16 =  32,768
  float* part1 = ws + 491520;        // 16*64*2  = 2048
  float* part2 = ws + 493568;        // 32*16*2  = 1024
  float* part3 = ws + 494592;        // 64*4*2   = 512
  float* part4 = ws + 495104;        // 128*2*2  = 512
  float* part6 = ws + 495616;        // 128*3    = 384 (pad to 512)
  unsigned* flp = (unsigned*)(ws + 496128); // 3*18516 dwords (even-pair layout)

  resize_w_kernel<<<3*2160, 256, 0, stream>>>(img, tmp);
  resize_h_kernel<<<3*256, 256, 0, stream>>>(tmp, r256);

  TailArgs ta;
  ta.r256 = r256; ta.w1 = w1; ta.b1 = b1;
  ta.w2 = w2; ta.b2 = b2; ta.g1 = g1; ta.be1 = be1;
  ta.w3 = w3; ta.b3 = b3; ta.g2 = g2; ta.be2 = be2;
  ta.w4 = w4; ta.b4 = b4; ta.g3 = g3; ta.be3 = be3;
  ta.w5 = w5; ta.b5 = b5; ta.g4 = g4; ta.be4 = be4;
  ta.w6 = w6; ta.b6 = b6;
  ta.l0 = lut0; ta.l1 = lut1; ta.l2 = lut2;
  ta.c1 = c1; ta.c2 = c2; ta.c3 = c3; ta.c4 = c4;
  ta.part1 = part1; ta.part2 = part2; ta.part3 = part3; ta.part4 = part4; ta.part6 = part6;
  ta.flp = flp;
  void* kargs[] = { (void*)&ta };
  hipLaunchCooperativeKernel(tail_fused, dim3(256), dim3(256), kargs, 0, stream);

  trilinear_kernel<<<768, 1024, 0, stream>>>(img, flp, (float*)d_out);
}

// Round 17
// 164.924 us; speedup vs baseline: 1.8731x; 1.8731x over previous
//
#include <hip/hip_runtime.h>

#define NPX (2160*3840)
#define EPS 1e-5f

typedef float __attribute__((ext_vector_type(4))) fx4;

// ---------------- resize along W: (3,2160,3840) -> (3,2160,256) ----------------
// sample center = 15*i+7 (exact int); 29 taps, weights 15-|d|; wsum=225 (197 at edges).
__global__ __launch_bounds__(256) void resize_w_kernel(const float* __restrict__ img,
                                                       float* __restrict__ tmp) {
  __shared__ __align__(16) float row[3872];   // 16 zero | 3840 | 16 zero
  const int bh = blockIdx.x;            // c*2160 + h
  const float* src = img + (size_t)bh * 3840;
  const int tid = threadIdx.x;          // 256
  if (tid < 16) { row[tid] = 0.f; row[3856 + tid] = 0.f; }
  const float4* s4 = (const float4*)src;
  float4* r4 = (float4*)(row + 16);
  for (int i = tid; i < 960; i += 256) r4[i] = s4[i];
  __syncthreads();
  const int i = tid;
  const float* rp = row + 15*i + 9;     // = 16 + center-14
  float acc = 0.f;
  #pragma unroll
  for (int k = 0; k < 29; ++k) {
    const float w = (float)(15 - (k < 14 ? 14 - k : k - 14));
    acc = fmaf(w, rp[k], acc);
  }
  const float rcpw = (i == 0 || i == 255) ? (1.f/197.f) : (1.f/225.f);
  tmp[bh*256 + i] = acc * rcpw;
}

// ---------------- resize along H: (3,2160,256) -> (3,256,256) ----------------
__global__ __launch_bounds__(256) void resize_h_kernel(const float* __restrict__ tmp,
                                                       float* __restrict__ dst) {
  const int c = blockIdx.x >> 8;
  const int oh = blockIdx.x & 255;
  const int ow = threadIdx.x;           // 256
  const float sf = ((float)oh + 0.5f) * 8.4375f - 0.5f;
  int lo = (int)ceilf(sf - 8.4375f); if (lo < 0) lo = 0;
  int hi = (int)floorf(sf + 8.4375f); if (hi > 2159) hi = 2159;
  float acc = 0.f, wsum = 0.f;
  for (int j = lo; j <= hi; ++j) {
    const float w = 1.f - fabsf(sf - (float)j) * (16.f/135.f);
    acc = fmaf(w, tmp[(c*2160 + j)*256 + ow], acc);
    wsum += w;
  }
  dst[blockIdx.x*256 + ow] = acc / wsum;
}

// ---------------- fused conv3x3(s2,p1) + input-norm-on-stage + lrelu + stats ----------------
template<int CIN,int CICHUNK,int HIN,int WIN,int HOUT,int WOUT,int TH,int NPIN,int MODE>
__global__ __launch_bounds__(256) void conv_fused(
    const float* __restrict__ in, const float* __restrict__ wt, const float* __restrict__ bias,
    const float* __restrict__ pin, const float* __restrict__ gin, const float* __restrict__ bin,
    float* __restrict__ out, float* __restrict__ pout,
    const float* __restrict__ gself, const float* __restrict__ bself) {
  constexpr int NTW = WOUT/16;
  constexpr int NT  = (HOUT/TH)*NTW;
  constexpr int NCHUNK = CIN/CICHUNK;
  constexpr int HROWS = 2*TH + 1;
  constexpr int SLOTS = CICHUNK*HROWS*9;       // float4 slots per chunk
  constexpr float PHW_INV = 1.f/(float)(HIN*WIN);

  __shared__ float sx[CICHUNK*HROWS*36];
  __shared__ float wl[CIN*9];
  __shared__ float sA[CIN], sB[CIN];
  __shared__ float2 wred[4];

  const int co = blockIdx.x / NT;
  const int t  = blockIdx.x % NT;
  const int oh0 = (t / NTW)*TH, ow0 = (t % NTW)*16;
  const int tid = threadIdx.x;

  for (int i = tid; i < CIN*9; i += 256) wl[i] = wt[co*CIN*9 + i];
  if (NPIN > 0) {
    if (tid < CIN) {
      const float2* p2 = (const float2*)pin;
      float s = 0.f, q = 0.f;
      #pragma unroll 4
      for (int k = 0; k < NPIN; ++k) { float2 p = p2[tid*NPIN + k]; s += p.x; q += p.y; }
      const float m = s * PHW_INV;
      float var = q * PHW_INV - m*m; var = fmaxf(var, 0.f);
      const float A = gin[tid] * rsqrtf(var + EPS);
      sA[tid] = A; sB[tid] = bin[tid] - m*A;
    }
  }
  __syncthreads();

  const int ohl = tid >> 4, owl = tid & 15;
  const bool active = (ohl < TH);
  float acc = bias[co];

  for (int cc = 0; cc < NCHUNK; ++cc) {
    if (cc) __syncthreads();
    const int cb = cc*CICHUNK;
    for (int i = tid; i < SLOTS; i += 256) {
      const int ci_l = i / (HROWS*9);
      const int rem  = i - ci_l*(HROWS*9);
      const int r = rem / 9, q = rem - r*9;
      const int grow = 2*oh0 - 1 + r;
      const int ga   = 2*ow0 - 4 + 4*q;
      float4 v = make_float4(0.f,0.f,0.f,0.f);
      if (grow >= 0 && grow < HIN && ga >= 0) {
        v = *(const float4*)(in + ((size_t)(cb+ci_l)*HIN + grow)*WIN + ga);
        if (NPIN > 0) {
          const float A = sA[cb+ci_l], B = sB[cb+ci_l];
          v.x = fmaf(A, v.x, B); v.y = fmaf(A, v.y, B);
          v.z = fmaf(A, v.z, B); v.w = fmaf(A, v.w, B);
        }
      }
      *(float4*)&sx[(ci_l*HROWS + r)*36 + q*4] = v;
    }
    __syncthreads();
    if (active) {
      #pragma unroll 4
      for (int ci_l = 0; ci_l < CICHUNK; ++ci_l) {
        const float* sp = sx + ci_l*(HROWS*36);
        const float* wp = wl + (cb+ci_l)*9;
        #pragma unroll
        for (int kh = 0; kh < 3; ++kh) {
          const float* rp = sp + (2*ohl + kh)*36 + 3 + 2*owl;
          acc = fmaf(rp[0], wp[kh*3+0], acc);
          acc = fmaf(rp[1], wp[kh*3+1], acc);
          acc = fmaf(rp[2], wp[kh*3+2], acc);
        }
      }
    }
  }

  acc = acc >= 0.f ? acc : 0.2f*acc;
  if (active) out[(size_t)co*HOUT*WOUT + (oh0+ohl)*WOUT + ow0 + owl] = acc;

  float s = active ? acc : 0.f;
  float q = active ? acc*acc : 0.f;
  #pragma unroll
  for (int off = 32; off > 0; off >>= 1) {
    s += __shfl_down(s, off);
    q += __shfl_down(q, off);
  }
  if ((tid & 63) == 0) wred[tid >> 6] = make_float2(s, q);
  __syncthreads();
  if (tid == 0) {
    const float S = wred[0].x + wred[1].x + wred[2].x + wred[3].x;
    const float Q = wred[0].y + wred[1].y + wred[2].y + wred[3].y;
    if (MODE == 1) {
      ((float2*)pout)[co*NT + t] = make_float2(S, Q);
    } else {
      const float m = S / (float)(HOUT*WOUT);
      float var = Q / (float)(HOUT*WOUT) - m*m; var = fmaxf(var, 0.f);
      const float A = gself[co] * rsqrtf(var + EPS);
      pout[co*2]   = A;
      pout[co*2+1] = bself[co] - m*A;
    }
  }
}

// ---------------- conv5 (128ci,16x16 -> 1co,8x8) + lrelu + w6 dot partials ----------------
__global__ __launch_bounds__(256) void conv5_fused(const float* __restrict__ in,
    const float* __restrict__ wt, const float* __restrict__ bias,
    const float* __restrict__ pin, const float* __restrict__ gin, const float* __restrict__ bin,
    const float* __restrict__ w6, float* __restrict__ part) {
  __shared__ float sx[32*17*20];
  __shared__ float wl[128*9];
  __shared__ float sA[128], sB[128];
  __shared__ float red[256];
  const int co = blockIdx.x;
  const int tid = threadIdx.x;
  for (int i = tid; i < 1152; i += 256) wl[i] = wt[co*1152 + i];
  if (tid < 128) {
    const float2* p2 = (const float2*)pin;
    const float2 pa = p2[tid*2], pb = p2[tid*2+1];
    const float m = (pa.x + pb.x) * (1.f/256.f);
    float var = (pa.y + pb.y) * (1.f/256.f) - m*m; var = fmaxf(var, 0.f);
    const float A = gin[tid] * rsqrtf(var + EPS);
    sA[tid] = A; sB[tid] = bin[tid] - m*A;
  }
  __syncthreads();

  const int px = tid & 63, q = tid >> 6;
  const int ohl = px >> 3, owl = px & 7;
  float acc = 0.f;
  for (int cc = 0; cc < 4; ++cc) {
    if (cc) __syncthreads();
    const int cb = cc*32;
    for (int i = tid; i < 32*17*5; i += 256) {
      const int ci_l = i / 85;
      const int rem  = i - ci_l*85;
      const int r = rem / 5, qq = rem - r*5;
      const int grow = r - 1;
      const int ga   = 4*qq - 4;
      float4 v = make_float4(0.f,0.f,0.f,0.f);
      if (grow >= 0 && grow < 16 && ga >= 0) {
        v = *(const float4*)(in + ((size_t)(cb+ci_l)*16 + grow)*16 + ga);
        const float A = sA[cb+ci_l], B = sB[cb+ci_l];
        v.x = fmaf(A, v.x, B); v.y = fmaf(A, v.y, B);
        v.z = fmaf(A, v.z, B); v.w = fmaf(A, v.w, B);
      }
      *(float4*)&sx[(ci_l*17 + r)*20 + qq*4] = v;
    }
    __syncthreads();
    #pragma unroll 2
    for (int k = 0; k < 8; ++k) {
      const int ci_l = q*8 + k;
      const float* sp = sx + ci_l*340;
      const float* wp = wl + (cb+ci_l)*9;
      #pragma unroll
      for (int kh = 0; kh < 3; ++kh) {
        const float* rp = sp + (2*ohl + kh)*20 + 3 + 2*owl;
        acc = fmaf(rp[0], wp[kh*3+0], acc);
        acc = fmaf(rp[1], wp[kh*3+1], acc);
        acc = fmaf(rp[2], wp[kh*3+2], acc);
      }
    }
  }
  red[tid] = acc;
  __syncthreads();
  if (tid < 64) {
    float a = red[tid] + red[tid+64] + red[tid+128] + red[tid+192] + bias[co];
    a = a >= 0.f ? a : 0.2f*a;
    #pragma unroll
    for (int j = 0; j < 3; ++j) {
      float v = a * w6[(j*128 + co)*64 + tid];
      #pragma unroll
      for (int off = 32; off > 0; off >>= 1) v += __shfl_down(v, off);
      if (tid == 0) part[co*3 + j] = v;
    }
  }
}

// ---------------- blend + pack (even-pair layout) ----------------
// Per (b,g)-row of 33 values store 17 dwords: dword j = bf16(v[2j]) | bf16(v[2j+1])<<16.
// Channel stride padded to 18516 dwords for uint4 staging. 3*18513 useful entries.
__global__ __launch_bounds__(256) void blend_pack_kernel(const float* __restrict__ l0,
    const float* __restrict__ l1, const float* __restrict__ l2,
    const float* __restrict__ part, const float* __restrict__ b6,
    unsigned* __restrict__ flp) {
  __shared__ float sred[2][3];
  __shared__ float sp[3];
  const int tid = threadIdx.x;
  float a0 = 0.f, a1 = 0.f, a2 = 0.f;
  if (tid < 128) { a0 = part[tid*3]; a1 = part[tid*3+1]; a2 = part[tid*3+2]; }
  #pragma unroll
  for (int off = 32; off > 0; off >>= 1) {
    a0 += __shfl_down(a0, off);
    a1 += __shfl_down(a1, off);
    a2 += __shfl_down(a2, off);
  }
  if (tid < 128 && (tid & 63) == 0) {
    sred[tid >> 6][0] = a0; sred[tid >> 6][1] = a1; sred[tid >> 6][2] = a2;
  }
  __syncthreads();
  if (tid < 3) sp[tid] = sred[0][tid] + sred[1][tid] + b6[tid];
  __syncthreads();
  const int i = blockIdx.x*256 + tid;
  if (i >= 3*18513) return;
  const int c = i / 18513, rem = i - c*18513;
  const int row = rem / 17, j = rem - row*17;
  const int src = c*35937 + row*33 + 2*j;
  const float v0 = sp[0]*l0[src] + sp[1]*l1[src] + sp[2]*l2[src];
  float v1 = 0.f;
  if (2*j + 1 <= 32) v1 = sp[0]*l0[src+1] + sp[1]*l1[src+1] + sp[2]*l2[src+1];
  unsigned u0 = __float_as_uint(v0); u0 = (u0 + 0x7fffu + ((u0>>16)&1u)) >> 16;
  unsigned u1 = __float_as_uint(v1); u1 = (u1 + 0x7fffu + ((u1>>16)&1u)) >> 16;
  flp[c*18516 + rem] = u0 | (u1 << 16);
}

// ---------------- trilinear: XCD-swizzled (3 channels of a chunk share an XCD's L2) ----------------
__global__ __launch_bounds__(1024, 8) void trilinear_kernel(const float* __restrict__ img,
    const unsigned* __restrict__ flp, float* __restrict__ out) {
  __shared__ unsigned slut[18516];     // 74.1 KB -> 2 blocks/CU, 32 waves
  const int tid = threadIdx.x;
  // XCD swizzle: hardware assigns block b to XCD b%8. Map so each XCD owns 32
  // contiguous chunks and the 3 channels of one chunk run on the SAME XCD
  // nearly simultaneously -> 2nd/3rd image reads hit that XCD's L2.
  const int b = blockIdx.x;            // 768 = 8 XCD * 32 chunks * 3 ch
  const int x = b & 7;
  const int j = b >> 3;                // 0..95
  const int chunk = x*32 + j/3;
  const int c     = j % 3;
  {
    uint4* d4 = (uint4*)slut;
    const uint4* s4 = (const uint4*)(flp + c*18516);
    for (int i = tid; i < 4629; i += 1024) d4[i] = s4[i];
  }
  __syncthreads();
  const int p0 = chunk * 32400;        // 256 chunks * 32400 = 8,294,400
  const float* imR = img + p0;
  const float* imG = img + NPX + p0;
  const float* imB = img + 2*NPX + p0;
  float* op = out + (size_t)c*NPX + p0;
  for (int g = tid; g < 4050; g += 1024) {
    const int pA = 4*g;
    const int pB = pA + 16200;
    float rv[8], gv[8], bv[8], ov[8];
    {
      const float4 A = *(const float4*)(imR + pA);
      const float4 B = *(const float4*)(imR + pB);
      rv[0]=A.x; rv[1]=A.y; rv[2]=A.z; rv[3]=A.w;
      rv[4]=B.x; rv[5]=B.y; rv[6]=B.z; rv[7]=B.w;
    }
    {
      const float4 A = *(const float4*)(imG + pA);
      const float4 B = *(const float4*)(imG + pB);
      gv[0]=A.x; gv[1]=A.y; gv[2]=A.z; gv[3]=A.w;
      gv[4]=B.x; gv[5]=B.y; gv[6]=B.z; gv[7]=B.w;
    }
    {
      const float4 A = *(const float4*)(imB + pA);
      const float4 B = *(const float4*)(imB + pB);
      bv[0]=A.x; bv[1]=A.y; bv[2]=A.z; bv[3]=A.w;
      bv[4]=B.x; bv[5]=B.y; bv[6]=B.z; bv[7]=B.w;
    }
    #pragma unroll
    for (int k = 0; k < 8; ++k) {
      const float xr = rv[k]*32.f, xg = gv[k]*32.f, xb = bv[k]*32.f;
      // img is uniform [0,1): (int)x <= 31 guaranteed
      const int ir = (int)xr, ig = (int)xg, ib = (int)xb;
      const float fr = xr - (float)ir;
      const float fg = xg - (float)ig;
      const float fb = xb - (float)ib;
      const int rb = (ib*33 + ig)*17;
      const int jA = rb + (ir >> 1);
      const int jB = rb + ((ir + 1) >> 1);
      const unsigned sh = (ir & 1) * 16;
      const unsigned w0a = slut[jA],       w0b = slut[jB];
      const unsigned w1a = slut[jA + 17],  w1b = slut[jB + 17];
      const unsigned w2a = slut[jA + 561], w2b = slut[jB + 561];
      const unsigned w3a = slut[jA + 578], w3b = slut[jB + 578];
      // alignbit(hi=wb, lo=wa, sh): lo16 = v[ir], hi16 = v[ir+1]
      const unsigned r0 = __builtin_amdgcn_alignbit(w0b, w0a, sh);
      const unsigned r1 = __builtin_amdgcn_alignbit(w1b, w1a, sh);
      const unsigned r2 = __builtin_amdgcn_alignbit(w2b, w2a, sh);
      const unsigned r3 = __builtin_amdgcn_alignbit(w3b, w3a, sh);
      const float v000 = __uint_as_float(r0 << 16), v001 = __uint_as_float(r0 & 0xffff0000u);
      const float v010 = __uint_as_float(r1 << 16), v011 = __uint_as_float(r1 & 0xffff0000u);
      const float v100 = __uint_as_float(r2 << 16), v101 = __uint_as_float(r2 & 0xffff0000u);
      const float v110 = __uint_as_float(r3 << 16), v111 = __uint_as_float(r3 & 0xffff0000u);
      const float a0 = fmaf(fr, v001 - v000, v000);
      const float a1 = fmaf(fr, v011 - v010, v010);
      const float a2 = fmaf(fr, v101 - v100, v100);
      const float a3 = fmaf(fr, v111 - v110, v110);
      const float lo = fmaf(fg, a1 - a0, a0);
      const float hi = fmaf(fg, a3 - a2, a2);
      ov[k] = fmaf(fb, hi - lo, lo);
    }
    fx4 r0 = {ov[0], ov[1], ov[2], ov[3]};
    fx4 r1 = {ov[4], ov[5], ov[6], ov[7]};
    __builtin_nontemporal_store(r0, (fx4*)(op + pA));
    __builtin_nontemporal_store(r1, (fx4*)(op + pB));
  }
}

extern "C" void kernel_launch(void* const* d_in, const int* in_sizes, int n_in,
                              void* d_out, int out_size, void* d_ws, size_t ws_size,
                              hipStream_t stream) {
  const float* img  = (const float*)d_in[0];
  const float* lut0 = (const float*)d_in[1];
  const float* lut1 = (const float*)d_in[2];
  const float* lut2 = (const float*)d_in[3];
  const float* w1 = (const float*)d_in[4];  const float* b1  = (const float*)d_in[5];
  const float* g1 = (const float*)d_in[6];  const float* be1 = (const float*)d_in[7];
  const float* w2 = (const float*)d_in[8];  const float* b2  = (const float*)d_in[9];
  const float* g2 = (const float*)d_in[10]; const float* be2 = (const float*)d_in[11];
  const float* w3 = (const float*)d_in[12]; const float* b3  = (const float*)d_in[13];
  const float* g3 = (const float*)d_in[14]; const float* be3 = (const float*)d_in[15];
  const float* w4 = (const float*)d_in[16]; const float* b4  = (const float*)d_in[17];
  const float* g4 = (const float*)d_in[18]; const float* be4 = (const float*)d_in[19];
  const float* w5 = (const float*)d_in[20]; const float* b5  = (const float*)d_in[21];
  const float* w6 = (const float*)d_in[22]; const float* b6  = (const float*)d_in[23];

  float* ws = (float*)d_ws;
  float* tmp   = ws;                 // 3*2160*256 = 1,658,880 (dead after resize_h)
  float* r256  = ws + 1658880;       // 3*256*256 = 196,608
  float* c1    = ws;                 // 16*128*128 = 262,144 (tmp dead)
  float* c2    = ws + 262144;        // 32*64*64  = 131,072
  float* c3    = ws + 393216;        // 64*32*32  =  65,536
  float* c4    = ws + 458752;        // 128*16*16 =  32,768
  float* part1 = ws + 491520;        // 16*64*2  = 2048
  float* part2 = ws + 493568;        // 32*16*2  = 1024
  float* part3 = ws + 494592;        // 64*4*2   = 512
  float* part4 = ws + 495104;        // 128*2*2  = 512
  float* part6 = ws + 495616;        // 128*3    = 384 (pad to 512)
  unsigned* flp = (unsigned*)(ws + 496128); // 3*18516 dwords (even-pair layout)

  resize_w_kernel<<<3*2160, 256, 0, stream>>>(img, tmp);
  resize_h_kernel<<<3*256, 256, 0, stream>>>(tmp, r256);

  conv_fused< 3, 3,256,256,128,128,16, 0,1><<<16*64, 256, 0, stream>>>(
      r256, w1, b1, nullptr, nullptr, nullptr, c1, part1, nullptr, nullptr);
  conv_fused<16,16,128,128, 64, 64,16,64,1><<<32*16, 256, 0, stream>>>(
      c1, w2, b2, part1, g1, be1, c2, part2, nullptr, nullptr);
  conv_fused<32,32, 64, 64, 32, 32,16,16,1><<<64*4, 256, 0, stream>>>(
      c2, w3, b3, part2, g2, be2, c3, part3, nullptr, nullptr);
  conv_fused<64,32, 32, 32, 16, 16, 8, 4,1><<<128*2, 256, 0, stream>>>(
      c3, w4, b4, part3, g3, be3, c4, part4, nullptr, nullptr);
  conv5_fused<<<128, 256, 0, stream>>>(c4, w5, b5, part4, g4, be4, w6, part6);

  blend_pack_kernel<<<218, 256, 0, stream>>>(lut0, lut1, lut2, part6, b6, flp);
  trilinear_kernel<<<768, 1024, 0, stream>>>(img, flp, (float*)d_out);
}